// Round 8
// baseline (447.691 us; speedup 1.0000x reference)
//
#include <hip/hip_runtime.h>
#include <hip/hip_bf16.h>
#include <hip/hip_fp16.h>
#include <math.h>

// Problem constants
#define BB   8
#define CIN  512
#define HH   64
#define WW   64
#define COUT 128
#define HW   4096        // HH*WW
#define PIX  32768       // BB*HW
#define MAXOFF 16.0f     // min(H,W)//4

// Workspace layout (float offsets)
#define OFF_XT      0ull            // x transposed NHWC: 8*4096*512        = 16,777,216
#define OFF_PARTIAL 16777216ull     // conv27 output [8][27][4096]          =    884,736
#define OFF_IMG     17661952ull     // pre-swizzled bf16 proj_w LDS image   =    294,912
#define OFF_A27     17956864ull     // pre-swizzled bf16 off/mod-w image    =     73,728
#define OFF_STATS   18030592ull     // mean[128], rstd[128]
// total = 18,030,848 floats = 72.1 MB

typedef short bf16x8 __attribute__((ext_vector_type(8)));
typedef unsigned short u16x8 __attribute__((ext_vector_type(8)));
typedef float f32x4  __attribute__((ext_vector_type(4)));
typedef float f32x16 __attribute__((ext_vector_type(16)));

__device__ __forceinline__ unsigned short f2bf(float f) {
    unsigned int u = __builtin_bit_cast(unsigned int, f);
    u += 0x7FFFu + ((u >> 16) & 1u);          // RNE (finite inputs)
    return (unsigned short)(u >> 16);
}

// global -> LDS direct DMA, 16B per lane. LDS dest: wave-uniform base + lane*16.
#define GLL16(gsrc, ldst) \
    __builtin_amdgcn_global_load_lds((const __attribute__((address_space(1))) void*)(gsrc), \
                                     (__attribute__((address_space(3))) void*)(ldst), 16, 0, 0)

// ---------------------------------------------------------------- transpose
// x [b][c][p] -> xt [b][p][c]   (p = h*64+w)
__global__ __launch_bounds__(256) void k_transpose(const float* __restrict__ x,
                                                   float* __restrict__ xt) {
    __shared__ float tile[32][33];
    int b  = blockIdx.z;
    int p0 = blockIdx.x * 32;
    int c0 = blockIdx.y * 32;
    int tx = threadIdx.x, ty = threadIdx.y;          // 32 x 8
    const float* src = x  + (size_t)b * CIN * HW;
    float*       dst = xt + (size_t)b * HW  * CIN;
    #pragma unroll
    for (int i = 0; i < 4; ++i)
        tile[ty + i*8][tx] = src[(size_t)(c0 + ty + i*8) * HW + p0 + tx];
    __syncthreads();
    #pragma unroll
    for (int i = 0; i < 4; ++i)
        dst[(size_t)(p0 + ty + i*8) * CIN + c0 + tx] = tile[tx][ty + i*8];
}

// ---------------------------------------------------------------- weight repack
// img: 72 blocks (tap*8+chsub) of [128 oc][64 c] bf16, XOR-swizzled LDS image of proj_w.
// a27: 72 blocks of [32 oc][64 c] bf16 (27 real + 5 zero rows), same swizzle, for conv27mm.
__global__ void k_prep_w(const float* __restrict__ proj_w,
                         const float* __restrict__ off_w,
                         const float* __restrict__ mod_w,
                         float* __restrict__ ws) {
    unsigned int* img = (unsigned int*)(ws + OFF_IMG);   // 294,912 u32 words
    unsigned int* a27 = (unsigned int*)(ws + OFF_A27);   //  73,728 u32 words
    const int nimg  = 294912;
    const int total = nimg + 73728;
    for (int i = blockIdx.x * blockDim.x + threadIdx.x; i < total;
         i += gridDim.x * blockDim.x) {
        if (i < nimg) {
            int pos = i * 2;                // halfword position
            int blk = pos >> 13;            // 0..71  (tap*8 + chsub)
            int k   = blk >> 3;
            int chb = (blk & 7) << 6;
            int idx = pos & 8191;
            int oc  = idx >> 6;
            int j   = idx & 63;             // even
            int sw  = (oc & 7) << 3;
            int c0  = chb + (j ^ sw);
            int c1  = chb + ((j + 1) ^ sw);
            unsigned short lo = f2bf(proj_w[(size_t)(oc * 512 + c0) * 9 + k]);
            unsigned short hi = f2bf(proj_w[(size_t)(oc * 512 + c1) * 9 + k]);
            img[i] = (unsigned int)lo | ((unsigned int)hi << 16);
        } else {
            int pos = (i - nimg) * 2;       // halfword into [72][32][64]
            int blk = pos >> 11;            // 0..71
            int k   = blk >> 3;
            int chb = (blk & 7) << 6;
            int idx = pos & 2047;
            int oc  = idx >> 6;             // 0..31
            int j   = idx & 63;             // even
            int sw  = (oc & 7) << 3;
            int c0  = chb + (j ^ sw);
            int c1  = chb + ((j + 1) ^ sw);
            float v0 = 0.f, v1 = 0.f;
            if (oc < 18)      { v0 = off_w[(size_t)(oc * 512 + c0) * 9 + k];
                                v1 = off_w[(size_t)(oc * 512 + c1) * 9 + k]; }
            else if (oc < 27) { v0 = mod_w[(size_t)((oc - 18) * 512 + c0) * 9 + k];
                                v1 = mod_w[(size_t)((oc - 18) * 512 + c1) * 9 + k]; }
            a27[i - nimg] = (unsigned int)f2bf(v0) | ((unsigned int)f2bf(v1) << 16);
        }
    }
}

// ---------------------------------------------------------------- offset/modulator conv as bf16 MFMA GEMM
// Block = (b,h) row, 512 thr (8 waves): D[32 oc][64 px], K = 9 taps x 512 c (72 iters of 64).
// XCD-swizzled blockIdx: XCD k processes all h of b=k (L2 locality for 3-row halos).
__global__ __launch_bounds__(512) void k_conv27mm(const float* __restrict__ xt,
                                                  const unsigned short* __restrict__ a27,
                                                  float* __restrict__ partial) {
    __shared__ __align__(16) unsigned short sB2[2][4096];   // [px][c] swizzled, 8 KB each
    __shared__ __align__(16) unsigned short sA2[2][2048];   // [oc][c] swizzled, 4 KB each

    int tid  = threadIdx.x;
    int wid  = tid >> 6;
    int lane = tid & 63;
    int sw_bid = ((blockIdx.x & 7) << 6) + (blockIdx.x >> 3);   // XCD-contiguous b
    int b    = sw_bid >> 6;
    int h    = sw_bid & 63;

    const float* xtb0  = xt + (size_t)b * HW * CIN;
    const uint4* a27u4 = (const uint4*)a27;

    int px = tid >> 3;                 // staging pixel 0..63
    int cl = (tid & 7) << 3;           // staging c-chunk base (8 c)
    int sdst = (px << 6) + (cl ^ ((px & 7) << 3));   // swizzled halfword offset

    f32x4 acc = {0.f, 0.f, 0.f, 0.f};

    // ---- prologue: stage iter 0 into buffer 0
    {
        if (wid < 4) GLL16(a27u4 + tid, (uint4*)&sA2[0][0] + (wid << 6));
        // tap 0: kh=0, kw=0 -> row=h-1, col=px-1
        int row = h - 1, col = px - 1;
        float4 f0 = {0,0,0,0}, f1 = {0,0,0,0};
        if (((unsigned)row < 64u) && ((unsigned)col < 64u)) {
            const float* src = xtb0 + ((size_t)(row * 64 + col) << 9) + cl;
            f0 = *(const float4*)src;
            f1 = *(const float4*)(src + 4);
        }
        u16x8 u;
        u[0] = f2bf(f0.x); u[1] = f2bf(f0.y); u[2] = f2bf(f0.z); u[3] = f2bf(f0.w);
        u[4] = f2bf(f1.x); u[5] = f2bf(f1.y); u[6] = f2bf(f1.z); u[7] = f2bf(f1.w);
        *(u16x8*)&sB2[0][sdst] = u;
    }
    __syncthreads();

    int m = wid & 1, n = wid >> 1;
    int oc_f = (m << 4) + (lane & 15);
    int px_f = (n << 4) + (lane & 15);
    int kq   = (lane >> 4) << 3;
    int swA  = (oc_f & 7) << 3;
    int swB  = (px_f & 7) << 3;

    int cur = 0;
    for (int it = 0; it < 72; ++it) {
        if (it + 1 < 72) {
            int nb  = cur ^ 1;
            int it1 = it + 1;
            int tap = it1 >> 3;
            int chb = (it1 & 7) << 6;
            int kh = tap / 3, kw = tap - kh * 3;
            if (wid < 4) GLL16(a27u4 + (size_t)it1 * 256 + tid, (uint4*)&sA2[nb][0] + (wid << 6));
            int row = h + kh - 1, col = px + kw - 1;
            float4 f0 = {0,0,0,0}, f1 = {0,0,0,0};
            if (((unsigned)row < 64u) && ((unsigned)col < 64u)) {
                const float* src = xtb0 + ((size_t)(row * 64 + col) << 9) + chb + cl;
                f0 = *(const float4*)src;
                f1 = *(const float4*)(src + 4);
            }
            u16x8 u;
            u[0] = f2bf(f0.x); u[1] = f2bf(f0.y); u[2] = f2bf(f0.z); u[3] = f2bf(f0.w);
            u[4] = f2bf(f1.x); u[5] = f2bf(f1.y); u[6] = f2bf(f1.z); u[7] = f2bf(f1.w);
            *(u16x8*)&sB2[nb][sdst] = u;
        }
        // GEMM on current buffer: one 16x16 tile per wave, K=64 (2 MFMA)
        {
            const unsigned short* Arow = &sA2[cur][oc_f << 6];
            const unsigned short* Brow = &sB2[cur][px_f << 6];
            #pragma unroll
            for (int kk = 0; kk < 2; ++kk) {
                int ci = (kk << 5) + kq;
                bf16x8 af = *(const bf16x8*)&Arow[ci ^ swA];
                bf16x8 bf = *(const bf16x8*)&Brow[ci ^ swB];
                acc = __builtin_amdgcn_mfma_f32_16x16x32_bf16(af, bf, acc, 0, 0, 0);
            }
        }
        __syncthreads();
        cur ^= 1;
    }

    // ---- epilogue: D col=lane&15 (px), row=(lane>>4)*4+r (oc); store oc<27
    int rowbase = (lane >> 4) << 2;
    #pragma unroll
    for (int r = 0; r < 4; ++r) {
        int oc = (m << 4) + rowbase + r;
        if (oc < 27)
            partial[((size_t)(b * 27 + oc) << 12) + (h << 6) + (n << 4) + (lane & 15)] = acc[r];
    }
}

// ---------------------------------------------------------------- fused deformable sample + projection (bf16 MFMA)
// Block = 512 thr (8 waves) = one (b,h) row: 128 oc x 64 px, K = 9 taps x 512 c (72 iters).
// Grid 512, LDS 56KB -> 2 blocks/CU. XCD-swizzled: XCD k runs all 64 h-blocks of b=k
// concurrently -> gather halos L2-resident. Gather: half-wave per px, float2 per lane.
__global__ __launch_bounds__(512, 4) void k_deform_proj(const float* __restrict__ xt,
                                                        const float* __restrict__ partial,
                                                        const float* __restrict__ off_b,
                                                        const float* __restrict__ mod_b,
                                                        const unsigned short* __restrict__ img,
                                                        float* __restrict__ out) {
    __shared__ unsigned int spos[9][64];                   // y0c|y1c<<6|x0c<<12|x1c<<18
    __shared__ uint2        swh [9][64];                   // 4 x fp16 validity-folded weights
    __shared__ __align__(16) unsigned short sA[2][4096];   // samples [px][c] swizzled (8 KB)
    __shared__ __align__(16) unsigned short sB[2][8192];   // weights [oc][c] swizzled (16 KB)

    int tid  = threadIdx.x;
    int wid  = tid >> 6;
    int lane = tid & 63;
    int sw_bid = ((blockIdx.x & 7) << 6) + (blockIdx.x >> 3);   // XCD-contiguous b
    int b    = sw_bid >> 6;
    int h    = sw_bid & 63;

    // ---- per-(pixel,tap) sampling params (9 taps x 64 px)
    for (int i = tid; i < 576; i += 512) {
        int k = i >> 6, px = i & 63;
        int hw = (h << 6) + px;
        const float* pp = partial + (size_t)(b * 27) * HW + hw;
        float oy = off_b[2 * k]     + pp[(size_t)(2 * k)     * HW];
        float ox = off_b[2 * k + 1] + pp[(size_t)(2 * k + 1) * HW];
        float om = mod_b[k]         + pp[(size_t)(18 + k)    * HW];
        oy = fminf(fmaxf(oy, -MAXOFF), MAXOFF);
        ox = fminf(fmaxf(ox, -MAXOFF), MAXOFF);
        float m = 2.f / (1.f + expf(-om));
        float py  = (float)h  + (float)(k / 3) - 1.f + oy;
        float pxf = (float)px + (float)(k % 3) - 1.f + ox;
        float y0f = floorf(py), x0f = floorf(pxf);
        float fy = py - y0f, fx = pxf - x0f;
        int iy0 = (int)y0f, ix0 = (int)x0f;
        bool y0v = (unsigned)iy0 < 64u, y1v = (unsigned)(iy0 + 1) < 64u;
        bool x0v = (unsigned)ix0 < 64u, x1v = (unsigned)(ix0 + 1) < 64u;
        int y0c = min(max(iy0, 0), 63),     y1c = min(max(iy0 + 1, 0), 63);
        int x0c = min(max(ix0, 0), 63),     x1c = min(max(ix0 + 1, 0), 63);
        float w00 = (1.f - fy) * (1.f - fx) * m * (float)(y0v && x0v);
        float w01 = (1.f - fy) * fx         * m * (float)(y0v && x1v);
        float w10 = fy         * (1.f - fx) * m * (float)(y1v && x0v);
        float w11 = fy         * fx         * m * (float)(y1v && x1v);
        spos[k][px] = (unsigned)y0c | ((unsigned)y1c << 6)
                    | ((unsigned)x0c << 12) | ((unsigned)x1c << 18);
        swh[k][px] = make_uint2(
            __builtin_bit_cast(unsigned int, __floats2half2_rn(w00, w01)),
            __builtin_bit_cast(unsigned int, __floats2half2_rn(w10, w11)));
    }
    __syncthreads();

    f32x16 acc = {0,0,0,0,0,0,0,0,0,0,0,0,0,0,0,0};

    const float* xtb0 = xt + (size_t)b * HW * CIN;
    int o  = wid & 3;                  // oc-tile (32 oc)
    int n  = wid >> 2;                 // px-tile (32 px)
    int swz   = (lane & 7) << 3;
    int khalf = (lane >> 5) << 3;
    int hpx   = (lane >> 5) << 2;      // gather: which px-quad of this wave's 8
    int cp    = (lane & 31) << 1;      // gather: c-pair base

    // ---- gather one iteration's A-tile into buffer nb
    #define GATHER(kT_, xtb_, nb_)                                                   \
        _Pragma("unroll")                                                            \
        for (int pp = 0; pp < 4; ++pp) {                                             \
            int px = (wid << 3) + hpx + pp;                                          \
            unsigned pk = spos[kT_][px];                                             \
            uint2 wp = swh[kT_][px];                                                 \
            float2 fA = __half22float2(__builtin_bit_cast(__half2, wp.x));           \
            float2 fB = __half22float2(__builtin_bit_cast(__half2, wp.y));           \
            int y0r = (pk & 63) << 6, y1r = ((pk >> 6) & 63) << 6;                   \
            int x0c = (pk >> 12) & 63, x1c = (pk >> 18) & 63;                        \
            const float* bs = (xtb_) + cp;                                           \
            float2 v00 = *(const float2*)&bs[(size_t)(y0r + x0c) << 9];              \
            float2 v01 = *(const float2*)&bs[(size_t)(y0r + x1c) << 9];              \
            float2 v10 = *(const float2*)&bs[(size_t)(y1r + x0c) << 9];              \
            float2 v11 = *(const float2*)&bs[(size_t)(y1r + x1c) << 9];              \
            float s0 = fA.x * v00.x + fA.y * v01.x + fB.x * v10.x + fB.y * v11.x;    \
            float s1 = fA.x * v00.y + fA.y * v01.y + fB.x * v10.y + fB.y * v11.y;    \
            unsigned uo = (unsigned)f2bf(s0) | ((unsigned)f2bf(s1) << 16);           \
            *(unsigned*)&sA[nb_][(px << 6) + (cp ^ ((px & 7) << 3))] = uo;           \
        }

    // ---- prologue: stage iter 0 into buffer 0
    {
        const uint4* bsrc = (const uint4*)img;
        uint4* ldsb = (uint4*)&sB[0][0];
        GLL16(bsrc + tid,       ldsb + (wid << 6));
        GLL16(bsrc + 512 + tid, ldsb + 512 + (wid << 6));
        GATHER(0, xtb0, 0)
    }
    __syncthreads();

    int cur = 0;
    for (int it = 0; it < 72; ++it) {
        // stage next tile into cur^1 (loads issued before GEMM for overlap)
        if (it + 1 < 72) {
            int nb = cur ^ 1;
            int kT = (it + 1) >> 3;
            int ch = ((it + 1) & 7) << 6;
            const uint4* bsrc = (const uint4*)(img + (size_t)(it + 1) * 8192);
            uint4* ldsb = (uint4*)&sB[nb][0];
            GLL16(bsrc + tid,       ldsb + (wid << 6));
            GLL16(bsrc + 512 + tid, ldsb + 512 + (wid << 6));
            const float* xtb = xtb0 + ch;
            GATHER(kT, xtb, nb)
        }
        // GEMM on current buffer: 32oc x 32px per wave, K=64 (4 MFMA)
        {
            const unsigned short* Wb = &sB[cur][((o << 5) + (lane & 31)) << 6];
            const unsigned short* S0 = &sA[cur][((n << 5) + (lane & 31)) << 6];
            #pragma unroll
            for (int kk = 0; kk < 4; ++kk) {
                int ci = ((kk << 4) + khalf) ^ swz;
                bf16x8 wf = *(const bf16x8*)&Wb[ci];
                bf16x8 s0 = *(const bf16x8*)&S0[ci];
                acc = __builtin_amdgcn_mfma_f32_32x32x16_bf16(wf, s0, acc, 0, 0, 0);
            }
        }
        __syncthreads();
        cur ^= 1;
    }
    #undef GATHER

    // ---- epilogue: D col = px = lane&31 -> coalesced 128B half-wave stores
    int oc_base = (o << 5) + ((lane >> 5) << 2);
    int px_c    = (n << 5) + (lane & 31);
    float* ob = out + (size_t)b * COUT * HW + (h << 6) + px_c;
    #pragma unroll
    for (int r = 0; r < 16; ++r) {
        int oc = oc_base + (r & 3) + ((r >> 2) << 3);
        ob[(size_t)oc << 12] = acc[r];
    }
}

// ---------------------------------------------------------------- BN statistics (per channel)
__global__ __launch_bounds__(256) void k_bn_stats(const float* __restrict__ pre,
                                                  float* __restrict__ stats) {
    int oc  = blockIdx.x;
    int tid = threadIdx.x;
    float s = 0.f, ss = 0.f;
    for (int i = tid; i < PIX; i += 256) {
        int b = i >> 12, hw = i & 4095;
        float v = pre[((size_t)(b * COUT + oc)) * HW + hw];
        s += v; ss += v * v;
    }
    #pragma unroll
    for (int off = 32; off > 0; off >>= 1) {
        s  += __shfl_down(s,  off, 64);
        ss += __shfl_down(ss, off, 64);
    }
    __shared__ float red[8];
    int wid = tid >> 6, lane = tid & 63;
    if (lane == 0) { red[wid] = s; red[4 + wid] = ss; }
    __syncthreads();
    if (tid == 0) {
        float S  = red[0] + red[1] + red[2] + red[3];
        float SS = red[4] + red[5] + red[6] + red[7];
        float mean = S / (float)PIX;
        float var  = SS / (float)PIX - mean * mean;
        stats[oc]       = mean;
        stats[128 + oc] = rsqrtf(var + 1e-5f);
    }
}

// ---------------------------------------------------------------- BN apply + exact GELU (in-place on d_out)
__global__ __launch_bounds__(256) void k_bn_gelu(float* __restrict__ out,
                                                 const float* __restrict__ stats,
                                                 const float* __restrict__ gamma,
                                                 const float* __restrict__ beta) {
    const int n4 = (BB * COUT * HW) / 4;   // 1,048,576 float4
    const float is2 = 0.70710678118654752f;
    for (int i = blockIdx.x * blockDim.x + threadIdx.x; i < n4;
         i += gridDim.x * blockDim.x) {
        int oc = (i >> 10) & 127;          // 1024 float4 per (b,oc) plane
        float g  = gamma[oc] * stats[128 + oc];
        float bt = beta[oc] - stats[oc] * g;
        float4 v = ((const float4*)out)[i];
        float4 r;
        float y;
        y = v.x * g + bt; r.x = 0.5f * y * (1.f + erff(y * is2));
        y = v.y * g + bt; r.y = 0.5f * y * (1.f + erff(y * is2));
        y = v.z * g + bt; r.z = 0.5f * y * (1.f + erff(y * is2));
        y = v.w * g + bt; r.w = 0.5f * y * (1.f + erff(y * is2));
        ((float4*)out)[i] = r;
    }
}

// ---------------------------------------------------------------- launch
extern "C" void kernel_launch(void* const* d_in, const int* in_sizes, int n_in,
                              void* d_out, int out_size, void* d_ws, size_t ws_size,
                              hipStream_t stream) {
    const float* x      = (const float*)d_in[0];
    const float* proj_w = (const float*)d_in[1];
    // d_in[2] = proj_b: per-channel constant, cancels exactly in BatchNorm -> unused
    const float* off_w  = (const float*)d_in[3];
    const float* off_b  = (const float*)d_in[4];
    const float* mod_w  = (const float*)d_in[5];
    const float* mod_b  = (const float*)d_in[6];
    const float* gamma  = (const float*)d_in[7];
    const float* beta   = (const float*)d_in[8];
    float* ws  = (float*)d_ws;
    float* out = (float*)d_out;

    k_transpose  <<<dim3(128, 16, 8), dim3(32, 8), 0, stream>>>(x, ws + OFF_XT);
    k_prep_w     <<<dim3(512), dim3(256), 0, stream>>>(proj_w, off_w, mod_w, ws);
    k_conv27mm   <<<dim3(512), dim3(512), 0, stream>>>(ws + OFF_XT,
                                                       (const unsigned short*)(ws + OFF_A27),
                                                       ws + OFF_PARTIAL);
    k_deform_proj<<<dim3(512), dim3(512), 0, stream>>>(ws + OFF_XT, ws + OFF_PARTIAL,
                                                       off_b, mod_b,
                                                       (const unsigned short*)(ws + OFF_IMG), out);
    k_bn_stats   <<<dim3(128), dim3(256), 0, stream>>>(out, ws + OFF_STATS);
    k_bn_gelu    <<<dim3(2048), dim3(256), 0, stream>>>(out, ws + OFF_STATS, gamma, beta);
}

// Round 9
// 329.457 us; speedup vs baseline: 1.3589x; 1.3589x over previous
//
#include <hip/hip_runtime.h>
#include <hip/hip_bf16.h>
#include <hip/hip_fp16.h>
#include <math.h>

// Problem constants
#define BB   8
#define CIN  512
#define HH   64
#define WW   64
#define COUT 128
#define HW   4096        // HH*WW
#define PIX  32768       // BB*HW
#define MAXOFF 16.0f     // min(H,W)//4

// Workspace layout (float offsets)
#define OFF_XT      0ull            // x transposed NHWC bf16: 8*4096*512 halfwords = 8,388,608 floats
#define OFF_PARTIAL 8388608ull      // conv27 output [8][27][4096]          =    884,736
#define OFF_IMG     9273344ull      // pre-swizzled bf16 proj_w LDS image   =    294,912
#define OFF_A27     9568256ull      // pre-swizzled bf16 off/mod-w image    =     73,728
#define OFF_STATS   9641984ull      // mean[128], rstd[128]
// total = 9,642,240 floats = 38.6 MB

typedef short bf16x8 __attribute__((ext_vector_type(8)));
typedef unsigned short u16x8 __attribute__((ext_vector_type(8)));
typedef float f32x4  __attribute__((ext_vector_type(4)));
typedef float f32x16 __attribute__((ext_vector_type(16)));

__device__ __forceinline__ unsigned short f2bf(float f) {
    unsigned int u = __builtin_bit_cast(unsigned int, f);
    u += 0x7FFFu + ((u >> 16) & 1u);          // RNE (finite inputs)
    return (unsigned short)(u >> 16);
}

// global -> LDS direct DMA, 16B per lane. LDS dest: wave-uniform base + lane*16.
#define GLL16(gsrc, ldst) \
    __builtin_amdgcn_global_load_lds((const __attribute__((address_space(1))) void*)(gsrc), \
                                     (__attribute__((address_space(3))) void*)(ldst), 16, 0, 0)

// ---------------------------------------------------------------- transpose + bf16 cast
// x [b][c][p] f32 -> xt [b][p][c] bf16   (p = h*64+w)
__global__ __launch_bounds__(256) void k_transpose(const float* __restrict__ x,
                                                   unsigned short* __restrict__ xt) {
    __shared__ float tile[32][33];
    int b  = blockIdx.z;
    int p0 = blockIdx.x * 32;
    int c0 = blockIdx.y * 32;
    int tx = threadIdx.x, ty = threadIdx.y;          // 32 x 8
    const float* src = x  + (size_t)b * CIN * HW;
    unsigned short* dst = xt + (size_t)b * HW * CIN;
    #pragma unroll
    for (int i = 0; i < 4; ++i)
        tile[ty + i*8][tx] = src[(size_t)(c0 + ty + i*8) * HW + p0 + tx];
    __syncthreads();
    int t = ty * 32 + tx;                            // 0..255
    #pragma unroll
    for (int i = 0; i < 2; ++i) {
        int j  = i * 256 + t;
        int pr = j >> 4;                             // p-row 0..31
        int cp = j & 15;                             // c-pair 0..15
        unsigned lo = f2bf(tile[2*cp][pr]);
        unsigned hi = f2bf(tile[2*cp+1][pr]);
        *(unsigned*)&dst[(size_t)(p0 + pr) * CIN + c0 + 2*cp] = lo | (hi << 16);
    }
}

// ---------------------------------------------------------------- weight repack
// img: 72 blocks (tap*8+chsub) of [128 oc][64 c] bf16, XOR-swizzled LDS image of proj_w.
// a27: 72 blocks of [32 oc][64 c] bf16 (27 real + 5 zero rows), same swizzle, for conv27mm.
__global__ void k_prep_w(const float* __restrict__ proj_w,
                         const float* __restrict__ off_w,
                         const float* __restrict__ mod_w,
                         float* __restrict__ ws) {
    unsigned int* img = (unsigned int*)(ws + OFF_IMG);   // 294,912 u32 words
    unsigned int* a27 = (unsigned int*)(ws + OFF_A27);   //  73,728 u32 words
    const int nimg  = 294912;
    const int total = nimg + 73728;
    for (int i = blockIdx.x * blockDim.x + threadIdx.x; i < total;
         i += gridDim.x * blockDim.x) {
        if (i < nimg) {
            int pos = i * 2;                // halfword position
            int blk = pos >> 13;            // 0..71  (tap*8 + chsub)
            int k   = blk >> 3;
            int chb = (blk & 7) << 6;
            int idx = pos & 8191;
            int oc  = idx >> 6;
            int j   = idx & 63;             // even
            int sw  = (oc & 7) << 3;
            int c0  = chb + (j ^ sw);
            int c1  = chb + ((j + 1) ^ sw);
            unsigned short lo = f2bf(proj_w[(size_t)(oc * 512 + c0) * 9 + k]);
            unsigned short hi = f2bf(proj_w[(size_t)(oc * 512 + c1) * 9 + k]);
            img[i] = (unsigned int)lo | ((unsigned int)hi << 16);
        } else {
            int pos = (i - nimg) * 2;       // halfword into [72][32][64]
            int blk = pos >> 11;            // 0..71
            int k   = blk >> 3;
            int chb = (blk & 7) << 6;
            int idx = pos & 2047;
            int oc  = idx >> 6;             // 0..31
            int j   = idx & 63;             // even
            int sw  = (oc & 7) << 3;
            int c0  = chb + (j ^ sw);
            int c1  = chb + ((j + 1) ^ sw);
            float v0 = 0.f, v1 = 0.f;
            if (oc < 18)      { v0 = off_w[(size_t)(oc * 512 + c0) * 9 + k];
                                v1 = off_w[(size_t)(oc * 512 + c1) * 9 + k]; }
            else if (oc < 27) { v0 = mod_w[(size_t)((oc - 18) * 512 + c0) * 9 + k];
                                v1 = mod_w[(size_t)((oc - 18) * 512 + c1) * 9 + k]; }
            a27[i - nimg] = (unsigned int)f2bf(v0) | ((unsigned int)f2bf(v1) << 16);
        }
    }
}

// ---------------------------------------------------------------- offset/modulator conv as bf16 MFMA GEMM
// Block = (b,h) row, 512 thr (8 waves): D[32 oc][64 px], K = 9 taps x 512 c (72 iters of 64).
// xt already bf16 -> staging is a raw 16B copy (no conversion). XCD-swizzled blockIdx.
__global__ __launch_bounds__(512) void k_conv27mm(const unsigned short* __restrict__ xt,
                                                  const unsigned short* __restrict__ a27,
                                                  float* __restrict__ partial) {
    __shared__ __align__(16) unsigned short sB2[2][4096];   // [px][c] swizzled, 8 KB each
    __shared__ __align__(16) unsigned short sA2[2][2048];   // [oc][c] swizzled, 4 KB each

    int tid  = threadIdx.x;
    int wid  = tid >> 6;
    int lane = tid & 63;
    int sw_bid = ((blockIdx.x & 7) << 6) + (blockIdx.x >> 3);   // XCD-contiguous b
    int b    = sw_bid >> 6;
    int h    = sw_bid & 63;

    const unsigned short* xtb0 = xt + (size_t)b * HW * CIN;
    const uint4* a27u4 = (const uint4*)a27;

    int px = tid >> 3;                 // staging pixel 0..63
    int cl = (tid & 7) << 3;           // staging c-chunk base (8 c)
    int sdst = (px << 6) + (cl ^ ((px & 7) << 3));   // swizzled halfword offset

    f32x4 acc = {0.f, 0.f, 0.f, 0.f};

    // ---- prologue: stage iter 0 into buffer 0
    {
        if (wid < 4) GLL16(a27u4 + tid, (uint4*)&sA2[0][0] + (wid << 6));
        // tap 0: kh=0, kw=0 -> row=h-1, col=px-1
        int row = h - 1, col = px - 1;
        u16x8 u = {0,0,0,0,0,0,0,0};
        if (((unsigned)row < 64u) && ((unsigned)col < 64u))
            u = *(const u16x8*)&xtb0[((size_t)(row * 64 + col) << 9) + cl];
        *(u16x8*)&sB2[0][sdst] = u;
    }
    __syncthreads();

    int m = wid & 1, n = wid >> 1;
    int oc_f = (m << 4) + (lane & 15);
    int px_f = (n << 4) + (lane & 15);
    int kq   = (lane >> 4) << 3;
    int swA  = (oc_f & 7) << 3;
    int swB  = (px_f & 7) << 3;

    int cur = 0;
    for (int it = 0; it < 72; ++it) {
        if (it + 1 < 72) {
            int nb  = cur ^ 1;
            int it1 = it + 1;
            int tap = it1 >> 3;
            int chb = (it1 & 7) << 6;
            int kh = tap / 3, kw = tap - kh * 3;
            if (wid < 4) GLL16(a27u4 + (size_t)it1 * 256 + tid, (uint4*)&sA2[nb][0] + (wid << 6));
            int row = h + kh - 1, col = px + kw - 1;
            u16x8 u = {0,0,0,0,0,0,0,0};
            if (((unsigned)row < 64u) && ((unsigned)col < 64u))
                u = *(const u16x8*)&xtb0[((size_t)(row * 64 + col) << 9) + chb + cl];
            *(u16x8*)&sB2[nb][sdst] = u;
        }
        // GEMM on current buffer: one 16x16 tile per wave, K=64 (2 MFMA)
        {
            const unsigned short* Arow = &sA2[cur][oc_f << 6];
            const unsigned short* Brow = &sB2[cur][px_f << 6];
            #pragma unroll
            for (int kk = 0; kk < 2; ++kk) {
                int ci = (kk << 5) + kq;
                bf16x8 af = *(const bf16x8*)&Arow[ci ^ swA];
                bf16x8 bf = *(const bf16x8*)&Brow[ci ^ swB];
                acc = __builtin_amdgcn_mfma_f32_16x16x32_bf16(af, bf, acc, 0, 0, 0);
            }
        }
        __syncthreads();
        cur ^= 1;
    }

    // ---- epilogue: D col=lane&15 (px), row=(lane>>4)*4+r (oc); store oc<27
    int rowbase = (lane >> 4) << 2;
    #pragma unroll
    for (int r = 0; r < 4; ++r) {
        int oc = (m << 4) + rowbase + r;
        if (oc < 27)
            partial[((size_t)(b * 27 + oc) << 12) + (h << 6) + (n << 4) + (lane & 15)] = acc[r];
    }
}

// ---------------------------------------------------------------- fused deformable sample + projection (bf16 MFMA)
// Block = 512 thr (8 waves) = one (b,h) row: 128 oc x 64 px, K = 9 taps x 512 c (72 iters).
// xt is bf16 -> gather loads one u32 (c-pair) per corner, halving L2/L3/HBM bytes.
// Grid 512, LDS 56KB -> 2 blocks/CU. XCD-swizzled for L2-local gather halos.
__global__ __launch_bounds__(512, 4) void k_deform_proj(const unsigned short* __restrict__ xt,
                                                        const float* __restrict__ partial,
                                                        const float* __restrict__ off_b,
                                                        const float* __restrict__ mod_b,
                                                        const unsigned short* __restrict__ img,
                                                        float* __restrict__ out) {
    __shared__ unsigned int spos[9][64];                   // y0c|y1c<<6|x0c<<12|x1c<<18
    __shared__ uint2        swh [9][64];                   // 4 x fp16 validity-folded weights
    __shared__ __align__(16) unsigned short sA[2][4096];   // samples [px][c] swizzled (8 KB)
    __shared__ __align__(16) unsigned short sB[2][8192];   // weights [oc][c] swizzled (16 KB)

    int tid  = threadIdx.x;
    int wid  = tid >> 6;
    int lane = tid & 63;
    int sw_bid = ((blockIdx.x & 7) << 6) + (blockIdx.x >> 3);   // XCD-contiguous b
    int b    = sw_bid >> 6;
    int h    = sw_bid & 63;

    // ---- per-(pixel,tap) sampling params (9 taps x 64 px)
    for (int i = tid; i < 576; i += 512) {
        int k = i >> 6, px = i & 63;
        int hw = (h << 6) + px;
        const float* pp = partial + (size_t)(b * 27) * HW + hw;
        float oy = off_b[2 * k]     + pp[(size_t)(2 * k)     * HW];
        float ox = off_b[2 * k + 1] + pp[(size_t)(2 * k + 1) * HW];
        float om = mod_b[k]         + pp[(size_t)(18 + k)    * HW];
        oy = fminf(fmaxf(oy, -MAXOFF), MAXOFF);
        ox = fminf(fmaxf(ox, -MAXOFF), MAXOFF);
        float m = 2.f / (1.f + expf(-om));
        float py  = (float)h  + (float)(k / 3) - 1.f + oy;
        float pxf = (float)px + (float)(k % 3) - 1.f + ox;
        float y0f = floorf(py), x0f = floorf(pxf);
        float fy = py - y0f, fx = pxf - x0f;
        int iy0 = (int)y0f, ix0 = (int)x0f;
        bool y0v = (unsigned)iy0 < 64u, y1v = (unsigned)(iy0 + 1) < 64u;
        bool x0v = (unsigned)ix0 < 64u, x1v = (unsigned)(ix0 + 1) < 64u;
        int y0c = min(max(iy0, 0), 63),     y1c = min(max(iy0 + 1, 0), 63);
        int x0c = min(max(ix0, 0), 63),     x1c = min(max(ix0 + 1, 0), 63);
        float w00 = (1.f - fy) * (1.f - fx) * m * (float)(y0v && x0v);
        float w01 = (1.f - fy) * fx         * m * (float)(y0v && x1v);
        float w10 = fy         * (1.f - fx) * m * (float)(y1v && x0v);
        float w11 = fy         * fx         * m * (float)(y1v && x1v);
        spos[k][px] = (unsigned)y0c | ((unsigned)y1c << 6)
                    | ((unsigned)x0c << 12) | ((unsigned)x1c << 18);
        swh[k][px] = make_uint2(
            __builtin_bit_cast(unsigned int, __floats2half2_rn(w00, w01)),
            __builtin_bit_cast(unsigned int, __floats2half2_rn(w10, w11)));
    }
    __syncthreads();

    f32x16 acc = {0,0,0,0,0,0,0,0,0,0,0,0,0,0,0,0};

    const unsigned short* xtb0 = xt + (size_t)b * HW * CIN;
    int o  = wid & 3;                  // oc-tile (32 oc)
    int n  = wid >> 2;                 // px-tile (32 px)
    int swz   = (lane & 7) << 3;
    int khalf = (lane >> 5) << 3;
    int hpx   = (lane >> 5) << 2;      // gather: which px-quad of this wave's 8
    int cp    = (lane & 31) << 1;      // gather: c-pair base (halfwords)

    // ---- gather one iteration's A-tile into buffer nb (bf16 source, u32 per corner)
    #define GATHER(kT_, xtb_, nb_)                                                   \
        _Pragma("unroll")                                                            \
        for (int pp = 0; pp < 4; ++pp) {                                             \
            int px = (wid << 3) + hpx + pp;                                          \
            unsigned pk = spos[kT_][px];                                             \
            uint2 wp = swh[kT_][px];                                                 \
            float2 fA = __half22float2(__builtin_bit_cast(__half2, wp.x));           \
            float2 fB = __half22float2(__builtin_bit_cast(__half2, wp.y));           \
            int y0r = (pk & 63) << 6, y1r = ((pk >> 6) & 63) << 6;                   \
            int x0c = (pk >> 12) & 63, x1c = (pk >> 18) & 63;                        \
            const unsigned short* bs = (xtb_) + cp;                                  \
            unsigned u00 = *(const unsigned*)&bs[(size_t)(y0r + x0c) << 9];          \
            unsigned u01 = *(const unsigned*)&bs[(size_t)(y0r + x1c) << 9];          \
            unsigned u10 = *(const unsigned*)&bs[(size_t)(y1r + x0c) << 9];          \
            unsigned u11 = *(const unsigned*)&bs[(size_t)(y1r + x1c) << 9];          \
            float a00 = __builtin_bit_cast(float, u00 << 16);                        \
            float a01 = __builtin_bit_cast(float, u01 << 16);                        \
            float a10 = __builtin_bit_cast(float, u10 << 16);                        \
            float a11 = __builtin_bit_cast(float, u11 << 16);                        \
            float b00 = __builtin_bit_cast(float, u00 & 0xFFFF0000u);                \
            float b01 = __builtin_bit_cast(float, u01 & 0xFFFF0000u);                \
            float b10 = __builtin_bit_cast(float, u10 & 0xFFFF0000u);                \
            float b11 = __builtin_bit_cast(float, u11 & 0xFFFF0000u);                \
            float s0 = fA.x * a00 + fA.y * a01 + fB.x * a10 + fB.y * a11;            \
            float s1 = fA.x * b00 + fA.y * b01 + fB.x * b10 + fB.y * b11;            \
            unsigned uo = (unsigned)f2bf(s0) | ((unsigned)f2bf(s1) << 16);           \
            *(unsigned*)&sA[nb_][(px << 6) + (cp ^ ((px & 7) << 3))] = uo;           \
        }

    // ---- prologue: stage iter 0 into buffer 0
    {
        const uint4* bsrc = (const uint4*)img;
        uint4* ldsb = (uint4*)&sB[0][0];
        GLL16(bsrc + tid,       ldsb + (wid << 6));
        GLL16(bsrc + 512 + tid, ldsb + 512 + (wid << 6));
        GATHER(0, xtb0, 0)
    }
    __syncthreads();

    int cur = 0;
    for (int it = 0; it < 72; ++it) {
        // stage next tile into cur^1 (loads issued before GEMM for overlap)
        if (it + 1 < 72) {
            int nb = cur ^ 1;
            int kT = (it + 1) >> 3;
            int ch = ((it + 1) & 7) << 6;
            const uint4* bsrc = (const uint4*)(img + (size_t)(it + 1) * 8192);
            uint4* ldsb = (uint4*)&sB[nb][0];
            GLL16(bsrc + tid,       ldsb + (wid << 6));
            GLL16(bsrc + 512 + tid, ldsb + 512 + (wid << 6));
            const unsigned short* xtb = xtb0 + ch;
            GATHER(kT, xtb, nb)
        }
        // GEMM on current buffer: 32oc x 32px per wave, K=64 (4 MFMA)
        {
            const unsigned short* Wb = &sB[cur][((o << 5) + (lane & 31)) << 6];
            const unsigned short* S0 = &sA[cur][((n << 5) + (lane & 31)) << 6];
            #pragma unroll
            for (int kk = 0; kk < 4; ++kk) {
                int ci = ((kk << 4) + khalf) ^ swz;
                bf16x8 wf = *(const bf16x8*)&Wb[ci];
                bf16x8 s0 = *(const bf16x8*)&S0[ci];
                acc = __builtin_amdgcn_mfma_f32_32x32x16_bf16(wf, s0, acc, 0, 0, 0);
            }
        }
        __syncthreads();
        cur ^= 1;
    }
    #undef GATHER

    // ---- epilogue: D col = px = lane&31 -> coalesced 128B half-wave stores
    int oc_base = (o << 5) + ((lane >> 5) << 2);
    int px_c    = (n << 5) + (lane & 31);
    float* ob = out + (size_t)b * COUT * HW + (h << 6) + px_c;
    #pragma unroll
    for (int r = 0; r < 16; ++r) {
        int oc = oc_base + (r & 3) + ((r >> 2) << 3);
        ob[(size_t)oc << 12] = acc[r];
    }
}

// ---------------------------------------------------------------- BN statistics (per channel)
__global__ __launch_bounds__(256) void k_bn_stats(const float* __restrict__ pre,
                                                  float* __restrict__ stats) {
    int oc  = blockIdx.x;
    int tid = threadIdx.x;
    float s = 0.f, ss = 0.f;
    for (int i = tid; i < PIX; i += 256) {
        int b = i >> 12, hw = i & 4095;
        float v = pre[((size_t)(b * COUT + oc)) * HW + hw];
        s += v; ss += v * v;
    }
    #pragma unroll
    for (int off = 32; off > 0; off >>= 1) {
        s  += __shfl_down(s,  off, 64);
        ss += __shfl_down(ss, off, 64);
    }
    __shared__ float red[8];
    int wid = tid >> 6, lane = tid & 63;
    if (lane == 0) { red[wid] = s; red[4 + wid] = ss; }
    __syncthreads();
    if (tid == 0) {
        float S  = red[0] + red[1] + red[2] + red[3];
        float SS = red[4] + red[5] + red[6] + red[7];
        float mean = S / (float)PIX;
        float var  = SS / (float)PIX - mean * mean;
        stats[oc]       = mean;
        stats[128 + oc] = rsqrtf(var + 1e-5f);
    }
}

// ---------------------------------------------------------------- BN apply + exact GELU (in-place on d_out)
__global__ __launch_bounds__(256) void k_bn_gelu(float* __restrict__ out,
                                                 const float* __restrict__ stats,
                                                 const float* __restrict__ gamma,
                                                 const float* __restrict__ beta) {
    const int n4 = (BB * COUT * HW) / 4;   // 1,048,576 float4
    const float is2 = 0.70710678118654752f;
    for (int i = blockIdx.x * blockDim.x + threadIdx.x; i < n4;
         i += gridDim.x * blockDim.x) {
        int oc = (i >> 10) & 127;          // 1024 float4 per (b,oc) plane
        float g  = gamma[oc] * stats[128 + oc];
        float bt = beta[oc] - stats[oc] * g;
        float4 v = ((const float4*)out)[i];
        float4 r;
        float y;
        y = v.x * g + bt; r.x = 0.5f * y * (1.f + erff(y * is2));
        y = v.y * g + bt; r.y = 0.5f * y * (1.f + erff(y * is2));
        y = v.z * g + bt; r.z = 0.5f * y * (1.f + erff(y * is2));
        y = v.w * g + bt; r.w = 0.5f * y * (1.f + erff(y * is2));
        ((float4*)out)[i] = r;
    }
}

// ---------------------------------------------------------------- launch
extern "C" void kernel_launch(void* const* d_in, const int* in_sizes, int n_in,
                              void* d_out, int out_size, void* d_ws, size_t ws_size,
                              hipStream_t stream) {
    const float* x      = (const float*)d_in[0];
    const float* proj_w = (const float*)d_in[1];
    // d_in[2] = proj_b: per-channel constant, cancels exactly in BatchNorm -> unused
    const float* off_w  = (const float*)d_in[3];
    const float* off_b  = (const float*)d_in[4];
    const float* mod_w  = (const float*)d_in[5];
    const float* mod_b  = (const float*)d_in[6];
    const float* gamma  = (const float*)d_in[7];
    const float* beta   = (const float*)d_in[8];
    float* ws  = (float*)d_ws;
    float* out = (float*)d_out;
    unsigned short* xt = (unsigned short*)(ws + OFF_XT);

    k_transpose  <<<dim3(128, 16, 8), dim3(32, 8), 0, stream>>>(x, xt);
    k_prep_w     <<<dim3(512), dim3(256), 0, stream>>>(proj_w, off_w, mod_w, ws);
    k_conv27mm   <<<dim3(512), dim3(512), 0, stream>>>(xt,
                                                       (const unsigned short*)(ws + OFF_A27),
                                                       ws + OFF_PARTIAL);
    k_deform_proj<<<dim3(512), dim3(512), 0, stream>>>(xt, ws + OFF_PARTIAL,
                                                       off_b, mod_b,
                                                       (const unsigned short*)(ws + OFF_IMG), out);
    k_bn_stats   <<<dim3(128), dim3(256), 0, stream>>>(out, ws + OFF_STATS);
    k_bn_gelu    <<<dim3(2048), dim3(256), 0, stream>>>(out, ws + OFF_STATS, gamma, beta);
}